// Round 10
// baseline (17776.311 us; speedup 1.0000x reference)
//
#include <hip/hip_runtime.h>

#define NG 8      // independent batch groups (16 rows each)

// Per-group flags, 128 B apart: [g*64]=fA (# L1 steps completed),
// [g*64+32]=fB (# L2 steps completed). Zeroed by init_kernel every launch.
__device__ __attribute__((aligned(128))) unsigned int g_cnt[NG * 64];

typedef __attribute__((ext_vector_type(8))) short short8;
typedef __attribute__((ext_vector_type(4))) float floatx4;

// Split fp32 v into bf16 hi + bf16 lo (residual), packed (hi<<16)|lo.
__device__ __forceinline__ unsigned int split_pack(float v) {
    unsigned int u  = __float_as_uint(v);
    unsigned int hb = u & 0xffff0000u;          // truncated-bf16 hi, exact in fp32
    float r = v - __uint_as_float(hb);          // exact residual
    return hb | (__float_as_uint(r) >> 16);
}

__device__ __forceinline__ float sigmoidf_(float z) {
    return 1.0f / (1.0f + __expf(-z));
}

// ---- r4-proven device-coherent primitives ----
// sc1 stores write through to the coherence point; sc1 u64 loads (coalesced,
// block-cooperative ONLY -- r3/r9 lesson: per-lane sc1 gathers are L3
// transaction-bound, 2x regression) fetch fresh from L3. Relaxed RMW spin is
// memory-side at L3 (never stale, no cache maintenance). No acquire fence =>
// weights/x stay L1/L2-warm for all 512 steps.
__device__ __forceinline__ void st_coh(unsigned int* p, unsigned int v) {
    __hip_atomic_store(p, v, __ATOMIC_RELAXED, __HIP_MEMORY_SCOPE_AGENT);
}
__device__ __forceinline__ unsigned long long ld_coh64(const unsigned long long* p) {
    return __hip_atomic_load(p, __ATOMIC_RELAXED, __HIP_MEMORY_SCOPE_AGENT);
}
__device__ __forceinline__ unsigned int ld_rmw(unsigned int* p) {
    return __hip_atomic_fetch_add(p, 0u, __ATOMIC_RELAXED, __HIP_MEMORY_SCOPE_AGENT);
}
__device__ __forceinline__ void arrive(unsigned int* cnt) {
    // fire-and-forget on the issuing side: result unused => no wait
    __hip_atomic_fetch_add(cnt, 1u, __ATOMIC_RELEASE, __HIP_MEMORY_SCOPE_AGENT);
}
__device__ __forceinline__ unsigned int spin_ge_ret(unsigned int* cnt, unsigned int target) {
    unsigned int v = ld_rmw(cnt);
    while (v < target) v = ld_rmw(cnt);
    return v;
}

// Unpack 8 packed hi/lo uints from swizzled LDS (i0 4-uint aligned; the
// second uint4 of the 8-chunk lives at i0 ^ 4; swizzle flips bits 2-4 only).
__device__ __forceinline__ void unpack_lds(const unsigned int* lp, int i0, short8& ah, short8& al) {
    uint4 pa = *(const uint4*)(lp + i0);
    uint4 pb = *(const uint4*)(lp + (i0 ^ 4));
    unsigned int pv[8] = {pa.x, pa.y, pa.z, pa.w, pb.x, pb.y, pb.z, pb.w};
#pragma unroll
    for (int j = 0; j < 8; ++j) {
        ah[j] = (short)(pv[j] >> 16);
        al[j] = (short)(pv[j] & 0xffffu);
    }
}

__device__ __forceinline__ void cvt_x(const float* xp, short8& ah, short8& al) {
    float4 xa = *(const float4*)(xp);
    float4 xb = *(const float4*)(xp + 4);
    float xv[8] = {xa.x, xa.y, xa.z, xa.w, xb.x, xb.y, xb.z, xb.w};
#pragma unroll
    for (int j = 0; j < 8; ++j) {
        unsigned int u  = __float_as_uint(xv[j]);
        unsigned int hb = u & 0xffff0000u;
        float r = xv[j] - __uint_as_float(hb);
        ah[j] = (short)(u >> 16);
        al[j] = (short)(__float_as_uint(r) >> 16);
    }
}

// ================= Layer-1 block (one per group, 1024 threads) =============
// Owns the ENTIRE group's layer1: 16 waves x 16 units = 256 units, 16 rows.
// The recurrence h1[s-1] -> h1[s] lives in an LDS double buffer: the serial
// chain has NO L3 round-trips (r4's ~2.9us/step sync cost). Publishes h1[s]
// to a 3-slot global ring (sc1, fire-and-forget) for the L2 block;
// backpressure poll on fB is slack-3 and cached => amortized ~1/3 steps.
// MFMA 16x16x32_bf16: A: m=lane&15,k=quad*8+j ; D: col=lane&15, row=quad*4+r
__device__ void lstm1_role(const float* __restrict__ x,
                           const float* __restrict__ W1, const float* __restrict__ U1,
                           const float* __restrict__ b1,
                           unsigned int* __restrict__ h1g,
                           unsigned int* __restrict__ fA, unsigned int* __restrict__ fB,
                           int m0, float (*zex)[17], unsigned int* __restrict__ ldsH)
{
    const int tid  = threadIdx.x;
    const int wv   = tid >> 6;
    const int lane = tid & 63;
    const int n    = lane & 15;
    const int quad = lane >> 4;
    const int gate = n >> 2;
    const int u0   = wv * 16;             // 16 units per wave (4 coltiles x 4)
    const int b_l  = lane >> 2;
    const int ul   = lane & 3;
    const int sw   = (n & 7) << 2;
    const int arow = m0 + n;

    // ---- one-time: weight B-fragments (hi/lo split), bias: 320 VGPRs ----
    short8 bh[4][10], bl[4][10];
    float bias_v[4];
#pragma unroll
    for (int c = 0; c < 4; ++c) {
        const int col = gate * 256 + u0 + c * 4 + (n & 3);
        bias_v[c] = b1[col];
#pragma unroll
        for (int kc = 0; kc < 10; ++kc)
#pragma unroll
            for (int j = 0; j < 8; ++j) {
                int k = kc * 32 + quad * 8 + j;
                float w = (k < 64) ? W1[k * 1024 + col] : U1[(k - 64) * 1024 + col];
                unsigned int p = split_pack(w);
                bh[c][kc][j] = (short)(p >> 16);
                bl[c][kc][j] = (short)(p & 0xffffu);
            }
    }

    // ---- zero the "step -1" LDS h buffer (buffer 1) ----
    {
        uint4 z = {0u, 0u, 0u, 0u};
        *(uint4*)(ldsH + 4096 + tid * 4) = z;
    }
    float cst[4] = {0.f, 0.f, 0.f, 0.f};
    __syncthreads();

    unsigned int fB_loc = 0u;
    for (int s = 0; s < 512; ++s) {
        const int prev = ((s & 1) ^ 1) * 4096;
        const int cur  = (s & 1) * 4096;
        const int slot = s % 3;

        floatx4 acc[4];
#pragma unroll
        for (int c = 0; c < 4; ++c)
            acc[c] = {bias_v[c], bias_v[c], bias_v[c], bias_v[c]};

        // x-part (kc 0..1): cache-resident, no recurrent dependency
        const float* xsrc = x + (size_t)arow * (512 * 64) + s * 64;
#pragma unroll
        for (int kc = 0; kc < 2; ++kc) {
            short8 ah, al;
            cvt_x(xsrc + kc * 32 + quad * 8, ah, al);
#pragma unroll
            for (int c = 0; c < 4; ++c) {
                acc[c] = __builtin_amdgcn_mfma_f32_16x16x32_bf16(ah, bh[c][kc], acc[c], 0, 0, 0);
                acc[c] = __builtin_amdgcn_mfma_f32_16x16x32_bf16(ah, bl[c][kc], acc[c], 0, 0, 0);
                acc[c] = __builtin_amdgcn_mfma_f32_16x16x32_bf16(al, bh[c][kc], acc[c], 0, 0, 0);
            }
        }
        // recurrent part (kc 2..9) from the LDS h buffer
#pragma unroll
        for (int kc = 2; kc < 10; ++kc) {
            short8 ah, al;
            unpack_lds(ldsH + prev, n * 256 + (((kc - 2) * 32 + quad * 8) ^ sw), ah, al);
#pragma unroll
            for (int c = 0; c < 4; ++c) {
                acc[c] = __builtin_amdgcn_mfma_f32_16x16x32_bf16(ah, bh[c][kc], acc[c], 0, 0, 0);
                acc[c] = __builtin_amdgcn_mfma_f32_16x16x32_bf16(ah, bl[c][kc], acc[c], 0, 0, 0);
                acc[c] = __builtin_amdgcn_mfma_f32_16x16x32_bf16(al, bh[c][kc], acc[c], 0, 0, 0);
            }
        }

        // ---- backpressure: writing ring slot s%3 overwrites h1[s-3]; L2
        // must have completed step s-3 (fB >= s-2). Slack 3 => poll rare. ----
        if (tid == 0 && s >= 3 && fB_loc < (unsigned)(s - 2))
            fB_loc = spin_ge_ret(fB, (unsigned)(s - 2));
        __syncthreads();                  // broadcast observation; gates stores

        // ---- epilogue: gates, h; write LDS (next step) + ring (for L2) ----
#pragma unroll
        for (int c = 0; c < 4; ++c) {
#pragma unroll
            for (int r = 0; r < 4; ++r) zex[quad * 4 + r][n] = acc[c][r];
            asm volatile("s_waitcnt lgkmcnt(0)" ::: "memory");
            float zi = zex[b_l][ 0 + ul];
            float zf = zex[b_l][ 4 + ul];
            float zg = zex[b_l][ 8 + ul];
            float zo = zex[b_l][12 + ul];
            asm volatile("s_waitcnt lgkmcnt(0)" ::: "memory");
            float ig = sigmoidf_(zi);
            float fg = sigmoidf_(zf);
            float gg = fmaxf(zg, 0.f);
            float og = sigmoidf_(zo);
            cst[c] = fg * cst[c] + ig * gg;
            float h = og * fmaxf(cst[c], 0.f);
            unsigned int p = split_pack(h);
            int u = u0 + c * 4 + ul;
            ldsH[cur + b_l * 256 + (u ^ ((b_l & 7) << 2))] = p;
            st_coh(&h1g[slot * 32768 + (m0 + b_l) * 256 + u], p);
        }
        // barrier drains all waves' sc1 stores (per-wave vmcnt(0) before
        // s_barrier) and publishes ldsH[cur] block-wide; then one arrival.
        __syncthreads();
        if (tid == 0) arrive(fA);
    }
}

// ================= Layer-2 block (one per group, 1024 threads) =============
// 16 waves x 8 units = 128 units. h2 recurrence entirely in LDS (never
// touches global!). h1[s] staged block-cooperatively from the ring (sc1,
// coalesced). Wait on fA is cached: L1 runs ahead => usually no poll.
__device__ void lstm2_role(const float* __restrict__ W2, const float* __restrict__ U2,
                           const float* __restrict__ b2,
                           unsigned int* __restrict__ h1g, float* __restrict__ out,
                           unsigned int* __restrict__ fA, unsigned int* __restrict__ fB,
                           int m0, float (*zex)[17],
                           unsigned int* __restrict__ ldsA, unsigned int* __restrict__ ldsH2)
{
    const int tid  = threadIdx.x;
    const int wv   = tid >> 6;
    const int lane = tid & 63;
    const int n    = lane & 15;
    const int quad = lane >> 4;
    const int gate = n >> 2;
    const int u0   = wv * 8;              // 8 units per wave (2 coltiles x 4)
    const int b_l  = lane >> 2;
    const int ul   = lane & 3;
    const int sw   = (n & 7) << 2;

    short8 bh[2][12], bl[2][12];
    float bias_v[2];
#pragma unroll
    for (int c = 0; c < 2; ++c) {
        const int col = gate * 128 + u0 + c * 4 + (n & 3);
        bias_v[c] = b2[col];
#pragma unroll
        for (int kc = 0; kc < 12; ++kc)
#pragma unroll
            for (int j = 0; j < 8; ++j) {
                int k = kc * 32 + quad * 8 + j;
                float w = (k < 256) ? W2[k * 512 + col] : U2[(k - 256) * 512 + col];
                unsigned int p = split_pack(w);
                bh[c][kc][j] = (short)(p >> 16);
                bl[c][kc][j] = (short)(p & 0xffffu);
            }
    }

    // zero the "step -1" LDS h2 buffer (buffer 1: 2048 uints)
    if (tid < 512) {
        uint4 z = {0u, 0u, 0u, 0u};
        *(uint4*)(ldsH2 + 2048 + tid * 4) = z;
    }
    float cst[2] = {0.f, 0.f};
    __syncthreads();

    unsigned int fA_loc = 0u;
    for (int s = 0; s < 512; ++s) {
        // ---- wait for h1[s] (cached flag; L1 leads so poll usually free) ----
        if (tid == 0 && fA_loc < (unsigned)(s + 1))
            fA_loc = spin_ge_ret(fA, (unsigned)(s + 1));
        __syncthreads();

        // ---- stage h1[s] (ring slot s%3) into swizzled LDS: 2048 u64,
        // 2 per thread, coalesced, loads issued before writes ----
        const int slot = s % 3;
        const unsigned long long* src =
            (const unsigned long long*)(h1g + slot * 32768 + m0 * 256);
        unsigned long long q0 = ld_coh64(src + tid);
        unsigned long long q1 = ld_coh64(src + tid + 1024);
        {
            int f = tid, row = f >> 7, cc = (f & 127) * 2;
            *(unsigned long long*)(ldsA + row * 256 + (cc ^ ((row & 7) << 2))) = q0;
            f = tid + 1024; row = f >> 7; cc = (f & 127) * 2;
            *(unsigned long long*)(ldsA + row * 256 + (cc ^ ((row & 7) << 2))) = q1;
        }
        __syncthreads();

        const int prev = ((s & 1) ^ 1) * 2048;
        const int cur  = (s & 1) * 2048;
        floatx4 acc[2];
#pragma unroll
        for (int c = 0; c < 2; ++c)
            acc[c] = {bias_v[c], bias_v[c], bias_v[c], bias_v[c]};

#pragma unroll
        for (int kc = 0; kc < 12; ++kc) {
            short8 ah, al;
            if (kc < 8) unpack_lds(ldsA, n * 256 + ((kc * 32 + quad * 8) ^ sw), ah, al);
            else        unpack_lds(ldsH2 + prev, n * 128 + (((kc - 8) * 32 + quad * 8) ^ sw), ah, al);
#pragma unroll
            for (int c = 0; c < 2; ++c) {
                acc[c] = __builtin_amdgcn_mfma_f32_16x16x32_bf16(ah, bh[c][kc], acc[c], 0, 0, 0);
                acc[c] = __builtin_amdgcn_mfma_f32_16x16x32_bf16(ah, bl[c][kc], acc[c], 0, 0, 0);
                acc[c] = __builtin_amdgcn_mfma_f32_16x16x32_bf16(al, bh[c][kc], acc[c], 0, 0, 0);
            }
        }

        // ---- epilogue ----
#pragma unroll
        for (int c = 0; c < 2; ++c) {
#pragma unroll
            for (int r = 0; r < 4; ++r) zex[quad * 4 + r][n] = acc[c][r];
            asm volatile("s_waitcnt lgkmcnt(0)" ::: "memory");
            float zi = zex[b_l][ 0 + ul];
            float zf = zex[b_l][ 4 + ul];
            float zg = zex[b_l][ 8 + ul];
            float zo = zex[b_l][12 + ul];
            asm volatile("s_waitcnt lgkmcnt(0)" ::: "memory");
            float ig = sigmoidf_(zi);
            float fg = sigmoidf_(zf);
            float gg = fmaxf(zg, 0.f);
            float og = sigmoidf_(zo);
            cst[c] = fg * cst[c] + ig * gg;
            float h = og * fmaxf(cst[c], 0.f);
            unsigned int p = split_pack(h);
            int u = u0 + c * 4 + ul;
            ldsH2[cur + b_l * 128 + (u ^ ((b_l & 7) << 2))] = p;
            if (s == 511) out[(m0 + b_l) * 128 + u] = h;
        }
        __syncthreads();
        if (tid == 0) arrive(fB);       // backpressure credit for L1
    }
}

__global__ void __launch_bounds__(1024, 1)
lstm_fused_kernel(const float* __restrict__ x,
                  const float* __restrict__ W1, const float* __restrict__ U1,
                  const float* __restrict__ b1,
                  const float* __restrict__ W2, const float* __restrict__ U2,
                  const float* __restrict__ b2,
                  float* __restrict__ out, unsigned int* __restrict__ ws)
{
    __shared__ float zex[16][16][17];        // per-wave gate-gather tiles
    __shared__ unsigned int ldsBuf[8192];    // L1: h1 dbuf | L2: ldsA + h2 dbuf
    unsigned int* h1g = ws;                  // [3][128][256] packed hi/lo bf16 ring
    const int g    = blockIdx.x & 7;         // batch group
    const int role = blockIdx.x >> 3;        // 0 = layer1, 1 = layer2
    const int wv   = threadIdx.x >> 6;
    const int m0   = g * 16;
    unsigned int* fA = &g_cnt[g * 64];
    unsigned int* fB = &g_cnt[g * 64 + 32];
    if (role == 0)
        lstm1_role(x, W1, U1, b1, h1g, fA, fB, m0, zex[wv], ldsBuf);
    else
        lstm2_role(W2, U2, b2, h1g, out, fA, fB, m0, zex[wv], ldsBuf, ldsBuf + 4096);
}

// Pre-kernel (plain launch, cannot fail): zero flags, write the diagnostic
// sentinel. Stream order publishes both to the main kernel.
// Failure signatures: absmax~7 => main never ran; absmax~0.162 => main ran
// but produced zeros (coherence issue).
__global__ void init_kernel(float* __restrict__ out) {
    int t = blockIdx.x * 256 + threadIdx.x;
    if (t < NG * 64) g_cnt[t] = 0u;
    if (t < 16384) out[t] = 7.0f;
}

extern "C" void kernel_launch(void* const* d_in, const int* in_sizes, int n_in,
                              void* d_out, int out_size, void* d_ws, size_t ws_size,
                              hipStream_t stream) {
    const float* x  = (const float*)d_in[0];
    const float* W1 = (const float*)d_in[1];
    const float* U1 = (const float*)d_in[2];
    const float* b1 = (const float*)d_in[3];
    const float* W2 = (const float*)d_in[4];
    const float* U2 = (const float*)d_in[5];
    const float* b2 = (const float*)d_in[6];
    float* out = (float*)d_out;
    unsigned int* ws = (unsigned int*)d_ws;
    init_kernel<<<64, 256, 0, stream>>>(out);
    lstm_fused_kernel<<<16, 1024, 0, stream>>>(x, W1, U1, b1, W2, U2, b2, out, ws);
}

// Round 11
// 17172.337 us; speedup vs baseline: 1.0352x; 1.0352x over previous
//
#include <hip/hip_runtime.h>

#define NG 8      // independent batch groups (16 rows each)

// Per-group flags, 128 B apart: [g*64]=fA (# L1 steps completed),
// [g*64+32]=fB (# L2 steps completed). Zeroed by init_kernel every launch.
__device__ __attribute__((aligned(128))) unsigned int g_cnt[NG * 64];

typedef __attribute__((ext_vector_type(8))) short short8;
typedef __attribute__((ext_vector_type(4))) float floatx4;

// Split fp32 v into bf16 hi + bf16 lo (residual), packed (hi<<16)|lo.
__device__ __forceinline__ unsigned int split_pack(float v) {
    unsigned int u  = __float_as_uint(v);
    unsigned int hb = u & 0xffff0000u;          // truncated-bf16 hi, exact in fp32
    float r = v - __uint_as_float(hb);          // exact residual
    return hb | (__float_as_uint(r) >> 16);
}

__device__ __forceinline__ float sigmoidf_(float z) {
    return 1.0f / (1.0f + __expf(-z));
}

// ---- r4-proven device-coherent primitives ----
// sc1 stores write through to the coherence point; sc1 u64 loads (coalesced,
// block-cooperative ONLY -- r3/r9 lesson) fetch fresh from L3. Relaxed RMW
// spin is memory-side at L3 (never stale, no cache maintenance). No acquire
// fence => weights/x stay L1/L2-warm for all 512 steps.
__device__ __forceinline__ void st_coh(unsigned int* p, unsigned int v) {
    __hip_atomic_store(p, v, __ATOMIC_RELAXED, __HIP_MEMORY_SCOPE_AGENT);
}
__device__ __forceinline__ unsigned long long ld_coh64(const unsigned long long* p) {
    return __hip_atomic_load(p, __ATOMIC_RELAXED, __HIP_MEMORY_SCOPE_AGENT);
}
__device__ __forceinline__ unsigned int ld_rmw(unsigned int* p) {
    return __hip_atomic_fetch_add(p, 0u, __ATOMIC_RELAXED, __HIP_MEMORY_SCOPE_AGENT);
}
__device__ __forceinline__ void arrive(unsigned int* cnt) {
    __hip_atomic_fetch_add(cnt, 1u, __ATOMIC_RELEASE, __HIP_MEMORY_SCOPE_AGENT);
}
__device__ __forceinline__ unsigned int spin_ge_ret(unsigned int* cnt, unsigned int target) {
    unsigned int v = ld_rmw(cnt);
    while (v < target) v = ld_rmw(cnt);
    return v;
}

// Unpack 8 packed hi/lo uints from swizzled LDS (i0 4-uint aligned; the
// second uint4 of the 8-chunk lives at i0 ^ 4; swizzle flips bits 2-4 only).
__device__ __forceinline__ void unpack_lds(const unsigned int* lp, int i0, short8& ah, short8& al) {
    uint4 pa = *(const uint4*)(lp + i0);
    uint4 pb = *(const uint4*)(lp + (i0 ^ 4));
    unsigned int pv[8] = {pa.x, pa.y, pa.z, pa.w, pb.x, pb.y, pb.z, pb.w};
#pragma unroll
    for (int j = 0; j < 8; ++j) {
        ah[j] = (short)(pv[j] >> 16);
        al[j] = (short)(pv[j] & 0xffffu);
    }
}

__device__ __forceinline__ void cvt_x(const float* xp, short8& ah, short8& al) {
    float4 xa = *(const float4*)(xp);
    float4 xb = *(const float4*)(xp + 4);
    float xv[8] = {xa.x, xa.y, xa.z, xa.w, xb.x, xb.y, xb.z, xb.w};
#pragma unroll
    for (int j = 0; j < 8; ++j) {
        unsigned int u  = __float_as_uint(xv[j]);
        unsigned int hb = u & 0xffff0000u;
        float r = xv[j] - __uint_as_float(hb);
        ah[j] = (short)(u >> 16);
        al[j] = (short)(__float_as_uint(r) >> 16);
    }
}

// ================= Layer-1 block (one per group, 1024 threads) =============
// Owns the ENTIRE group's layer1: 16 waves x 16 units = 256 units, 16 rows.
// Recurrence h1[s-1]->h1[s] lives in an LDS double buffer: NO L3 round-trips
// on the serial chain. Publishes h1[s] to a 3-slot global ring (sc1,
// fire-and-forget) for the L2 block; backpressure poll on fB is slack-3 and
// cached. FORCEINLINE is essential: r10's non-inlined call pushed the ~320
// weight VGPRs to scratch (VGPR_Count=64, 9x slowdown).
// MFMA 16x16x32_bf16: A: m=lane&15,k=quad*8+j ; D: col=lane&15, row=quad*4+r
__device__ __forceinline__ void lstm1_role(
    const float* __restrict__ x,
    const float* __restrict__ W1, const float* __restrict__ U1,
    const float* __restrict__ b1,
    unsigned int* __restrict__ h1g,
    unsigned int* __restrict__ fA, unsigned int* __restrict__ fB,
    int m0, float (*zex)[17], unsigned int* __restrict__ ldsH)
{
    const int tid  = threadIdx.x;
    const int wv   = tid >> 6;
    const int lane = tid & 63;
    const int n    = lane & 15;
    const int quad = lane >> 4;
    const int gate = n >> 2;
    const int u0   = wv * 16;             // 16 units per wave (4 coltiles x 4)
    const int b_l  = lane >> 2;
    const int ul   = lane & 3;
    const int sw   = (n & 7) << 2;
    const int arow = m0 + n;

    // ---- one-time: weight B-fragments (hi/lo split), bias (~320 VGPRs) ----
    short8 bh[4][10], bl[4][10];
    float bias_v[4];
#pragma unroll
    for (int c = 0; c < 4; ++c) {
        const int col = gate * 256 + u0 + c * 4 + (n & 3);
        bias_v[c] = b1[col];
#pragma unroll
        for (int kc = 0; kc < 10; ++kc)
#pragma unroll
            for (int j = 0; j < 8; ++j) {
                int k = kc * 32 + quad * 8 + j;
                float w = (k < 64) ? W1[k * 1024 + col] : U1[(k - 64) * 1024 + col];
                unsigned int p = split_pack(w);
                bh[c][kc][j] = (short)(p >> 16);
                bl[c][kc][j] = (short)(p & 0xffffu);
            }
    }

    // ---- zero the "step -1" LDS h buffer (buffer 1) ----
    {
        uint4 z = {0u, 0u, 0u, 0u};
        *(uint4*)(ldsH + 4096 + tid * 4) = z;
    }
    float cst[4] = {0.f, 0.f, 0.f, 0.f};
    __syncthreads();

    unsigned int fB_loc = 0u;
    for (int s = 0; s < 512; ++s) {
        const int prev = ((s & 1) ^ 1) * 4096;
        const int cur  = (s & 1) * 4096;
        const int slot = s % 3;

        floatx4 acc[4];
#pragma unroll
        for (int c = 0; c < 4; ++c)
            acc[c] = {bias_v[c], bias_v[c], bias_v[c], bias_v[c]};

        // x-part (kc 0..1): cache-resident, no recurrent dependency
        const float* xsrc = x + (size_t)arow * (512 * 64) + s * 64;
#pragma unroll
        for (int kc = 0; kc < 2; ++kc) {
            short8 ah, al;
            cvt_x(xsrc + kc * 32 + quad * 8, ah, al);
#pragma unroll
            for (int c = 0; c < 4; ++c) {
                acc[c] = __builtin_amdgcn_mfma_f32_16x16x32_bf16(ah, bh[c][kc], acc[c], 0, 0, 0);
                acc[c] = __builtin_amdgcn_mfma_f32_16x16x32_bf16(ah, bl[c][kc], acc[c], 0, 0, 0);
                acc[c] = __builtin_amdgcn_mfma_f32_16x16x32_bf16(al, bh[c][kc], acc[c], 0, 0, 0);
            }
        }
        // recurrent part (kc 2..9) from the LDS h buffer
#pragma unroll
        for (int kc = 2; kc < 10; ++kc) {
            short8 ah, al;
            unpack_lds(ldsH + prev, n * 256 + (((kc - 2) * 32 + quad * 8) ^ sw), ah, al);
#pragma unroll
            for (int c = 0; c < 4; ++c) {
                acc[c] = __builtin_amdgcn_mfma_f32_16x16x32_bf16(ah, bh[c][kc], acc[c], 0, 0, 0);
                acc[c] = __builtin_amdgcn_mfma_f32_16x16x32_bf16(ah, bl[c][kc], acc[c], 0, 0, 0);
                acc[c] = __builtin_amdgcn_mfma_f32_16x16x32_bf16(al, bh[c][kc], acc[c], 0, 0, 0);
            }
        }

        // ---- backpressure: writing ring slot s%3 overwrites h1[s-3]; L2
        // must have completed step s-3 (fB >= s-2). Slack 3 => poll rare. ----
        if (tid == 0 && s >= 3 && fB_loc < (unsigned)(s - 2))
            fB_loc = spin_ge_ret(fB, (unsigned)(s - 2));
        __syncthreads();                  // broadcast observation; gates stores

        // ---- epilogue: gates, h; write LDS (next step) + ring (for L2) ----
#pragma unroll
        for (int c = 0; c < 4; ++c) {
#pragma unroll
            for (int r = 0; r < 4; ++r) zex[quad * 4 + r][n] = acc[c][r];
            asm volatile("s_waitcnt lgkmcnt(0)" ::: "memory");
            float zi = zex[b_l][ 0 + ul];
            float zf = zex[b_l][ 4 + ul];
            float zg = zex[b_l][ 8 + ul];
            float zo = zex[b_l][12 + ul];
            asm volatile("s_waitcnt lgkmcnt(0)" ::: "memory");
            float ig = sigmoidf_(zi);
            float fg = sigmoidf_(zf);
            float gg = fmaxf(zg, 0.f);
            float og = sigmoidf_(zo);
            cst[c] = fg * cst[c] + ig * gg;
            float h = og * fmaxf(cst[c], 0.f);
            unsigned int p = split_pack(h);
            int u = u0 + c * 4 + ul;
            ldsH[cur + b_l * 256 + (u ^ ((b_l & 7) << 2))] = p;
            st_coh(&h1g[slot * 32768 + (m0 + b_l) * 256 + u], p);
        }
        // barrier drains all waves' sc1 stores (per-wave vmcnt(0) before
        // s_barrier) and publishes ldsH[cur] block-wide; then one arrival.
        __syncthreads();
        if (tid == 0) arrive(fA);
    }
}

// ================= Layer-2 block (one per group, 1024 threads) =============
// 16 waves x 8 units = 128 units. h2 recurrence entirely in LDS. h1[s]
// staged block-cooperatively from the ring into a DOUBLE-buffered ldsA with
// one-step PREFETCH: the loads for h1[s+1] are issued before step s's MFMAs,
// so the single L3 RTT in this chain hides under compute.
__device__ __forceinline__ void lstm2_role(
    const float* __restrict__ W2, const float* __restrict__ U2,
    const float* __restrict__ b2,
    unsigned int* __restrict__ h1g, float* __restrict__ out,
    unsigned int* __restrict__ fA, unsigned int* __restrict__ fB,
    int m0, float (*zex)[17],
    unsigned int* __restrict__ ldsA,      // double buffer: 2 x 4096 uints
    unsigned int* __restrict__ ldsH2)     // double buffer: 2 x 2048 uints
{
    const int tid  = threadIdx.x;
    const int wv   = tid >> 6;
    const int lane = tid & 63;
    const int n    = lane & 15;
    const int quad = lane >> 4;
    const int gate = n >> 2;
    const int u0   = wv * 8;              // 8 units per wave (2 coltiles x 4)
    const int b_l  = lane >> 2;
    const int ul   = lane & 3;
    const int sw   = (n & 7) << 2;

    short8 bh[2][12], bl[2][12];
    float bias_v[2];
#pragma unroll
    for (int c = 0; c < 2; ++c) {
        const int col = gate * 128 + u0 + c * 4 + (n & 3);
        bias_v[c] = b2[col];
#pragma unroll
        for (int kc = 0; kc < 12; ++kc)
#pragma unroll
            for (int j = 0; j < 8; ++j) {
                int k = kc * 32 + quad * 8 + j;
                float w = (k < 256) ? W2[k * 512 + col] : U2[(k - 256) * 512 + col];
                unsigned int p = split_pack(w);
                bh[c][kc][j] = (short)(p >> 16);
                bl[c][kc][j] = (short)(p & 0xffffu);
            }
    }

    // zero the "step -1" LDS h2 buffer (buffer 1: 2048 uints)
    if (tid < 512) {
        uint4 z = {0u, 0u, 0u, 0u};
        *(uint4*)(ldsH2 + 2048 + tid * 4) = z;
    }
    float cst[2] = {0.f, 0.f};

    // ---- prologue: wait h1[0], stage ring slot 0 into ldsA buffer 0 ----
    unsigned int fA_loc = 0u;
    if (tid == 0) fA_loc = spin_ge_ret(fA, 1u);
    __syncthreads();                       // gate published to all threads
    {
        const unsigned long long* src = (const unsigned long long*)(h1g + m0 * 256);
        unsigned long long q0 = ld_coh64(src + tid);
        unsigned long long q1 = ld_coh64(src + tid + 1024);
        int f = tid, row = f >> 7, cc = (f & 127) * 2;
        *(unsigned long long*)(ldsA + row * 256 + (cc ^ ((row & 7) << 2))) = q0;
        f = tid + 1024; row = f >> 7; cc = (f & 127) * 2;
        *(unsigned long long*)(ldsA + row * 256 + (cc ^ ((row & 7) << 2))) = q1;
    }
    __syncthreads();                       // ldsA[0] + ldsH2 zeros ready

    for (int s = 0; s < 512; ++s) {
        const int cura  = (s & 1) * 4096;
        const int nxta  = ((s & 1) ^ 1) * 4096;
        const int prevh = ((s & 1) ^ 1) * 2048;
        const int curh  = (s & 1) * 2048;
        const bool pf   = (s + 1 < 512);

        // ---- prefetch gate for h1[s+1] (cached; L1 leads => poll rare) ----
        if (tid == 0 && pf && fA_loc < (unsigned)(s + 2))
            fA_loc = spin_ge_ret(fA, (unsigned)(s + 2));
        __syncthreads();

        // issue prefetch loads (slot (s+1)%3); consumed after the MFMAs
        unsigned long long q0 = 0, q1 = 0;
        if (pf) {
            const unsigned long long* src =
                (const unsigned long long*)(h1g + ((s + 1) % 3) * 32768 + m0 * 256);
            q0 = ld_coh64(src + tid);
            q1 = ld_coh64(src + tid + 1024);
        }

        floatx4 acc[2];
#pragma unroll
        for (int c = 0; c < 2; ++c)
            acc[c] = {bias_v[c], bias_v[c], bias_v[c], bias_v[c]};

#pragma unroll
        for (int kc = 0; kc < 12; ++kc) {
            short8 ah, al;
            if (kc < 8) unpack_lds(ldsA + cura, n * 256 + ((kc * 32 + quad * 8) ^ sw), ah, al);
            else        unpack_lds(ldsH2 + prevh, n * 128 + (((kc - 8) * 32 + quad * 8) ^ sw), ah, al);
#pragma unroll
            for (int c = 0; c < 2; ++c) {
                acc[c] = __builtin_amdgcn_mfma_f32_16x16x32_bf16(ah, bh[c][kc], acc[c], 0, 0, 0);
                acc[c] = __builtin_amdgcn_mfma_f32_16x16x32_bf16(ah, bl[c][kc], acc[c], 0, 0, 0);
                acc[c] = __builtin_amdgcn_mfma_f32_16x16x32_bf16(al, bh[c][kc], acc[c], 0, 0, 0);
            }
        }

        // write prefetched h1[s+1] into the other ldsA buffer
        if (pf) {
            int f = tid, row = f >> 7, cc = (f & 127) * 2;
            *(unsigned long long*)(ldsA + nxta + row * 256 + (cc ^ ((row & 7) << 2))) = q0;
            f = tid + 1024; row = f >> 7; cc = (f & 127) * 2;
            *(unsigned long long*)(ldsA + nxta + row * 256 + (cc ^ ((row & 7) << 2))) = q1;
        }

        // ---- epilogue ----
#pragma unroll
        for (int c = 0; c < 2; ++c) {
#pragma unroll
            for (int r = 0; r < 4; ++r) zex[quad * 4 + r][n] = acc[c][r];
            asm volatile("s_waitcnt lgkmcnt(0)" ::: "memory");
            float zi = zex[b_l][ 0 + ul];
            float zf = zex[b_l][ 4 + ul];
            float zg = zex[b_l][ 8 + ul];
            float zo = zex[b_l][12 + ul];
            asm volatile("s_waitcnt lgkmcnt(0)" ::: "memory");
            float ig = sigmoidf_(zi);
            float fg = sigmoidf_(zf);
            float gg = fmaxf(zg, 0.f);
            float og = sigmoidf_(zo);
            cst[c] = fg * cst[c] + ig * gg;
            float h = og * fmaxf(cst[c], 0.f);
            unsigned int p = split_pack(h);
            int u = u0 + c * 4 + ul;
            ldsH2[curh + b_l * 128 + (u ^ ((b_l & 7) << 2))] = p;
            if (s == 511) out[(m0 + b_l) * 128 + u] = h;
        }
        __syncthreads();                   // publishes ldsA[nxta] + ldsH2[curh]
        if (tid == 0) arrive(fB);          // backpressure credit for L1
    }
}

__global__ void __launch_bounds__(1024, 1)
lstm_fused_kernel(const float* __restrict__ x,
                  const float* __restrict__ W1, const float* __restrict__ U1,
                  const float* __restrict__ b1,
                  const float* __restrict__ W2, const float* __restrict__ U2,
                  const float* __restrict__ b2,
                  float* __restrict__ out, unsigned int* __restrict__ ws)
{
    __shared__ float zex[16][16][17];        // per-wave gate-gather tiles
    __shared__ unsigned int ldsBuf[12288];   // L1: h1 dbuf(8192) | L2: ldsA dbuf(8192)+h2 dbuf(4096)
    unsigned int* h1g = ws;                  // [3][128][256] packed hi/lo bf16 ring
    const int g    = blockIdx.x & 7;         // batch group
    const int role = blockIdx.x >> 3;        // 0 = layer1, 1 = layer2
    const int wv   = threadIdx.x >> 6;
    const int m0   = g * 16;
    unsigned int* fA = &g_cnt[g * 64];
    unsigned int* fB = &g_cnt[g * 64 + 32];
    if (role == 0)
        lstm1_role(x, W1, U1, b1, h1g, fA, fB, m0, zex[wv], ldsBuf);
    else
        lstm2_role(W2, U2, b2, h1g, out, fA, fB, m0, zex[wv], ldsBuf, ldsBuf + 8192);
}

// Pre-kernel (plain launch, cannot fail): zero flags, write the diagnostic
// sentinel. Stream order publishes both to the main kernel.
// Failure signatures: absmax~7 => main never ran; absmax~0.162 => main ran
// but produced zeros (coherence issue).
__global__ void init_kernel(float* __restrict__ out) {
    int t = blockIdx.x * 256 + threadIdx.x;
    if (t < NG * 64) g_cnt[t] = 0u;
    if (t < 16384) out[t] = 7.0f;
}

extern "C" void kernel_launch(void* const* d_in, const int* in_sizes, int n_in,
                              void* d_out, int out_size, void* d_ws, size_t ws_size,
                              hipStream_t stream) {
    const float* x  = (const float*)d_in[0];
    const float* W1 = (const float*)d_in[1];
    const float* U1 = (const float*)d_in[2];
    const float* b1 = (const float*)d_in[3];
    const float* W2 = (const float*)d_in[4];
    const float* U2 = (const float*)d_in[5];
    const float* b2 = (const float*)d_in[6];
    float* out = (float*)d_out;
    unsigned int* ws = (unsigned int*)d_ws;
    init_kernel<<<64, 256, 0, stream>>>(out);
    lstm_fused_kernel<<<16, 1024, 0, stream>>>(x, W1, U1, b1, W2, U2, b2, out, ws);
}

// Round 12
// 3271.277 us; speedup vs baseline: 5.4341x; 5.2494x over previous
//
#include <hip/hip_runtime.h>

#define NG 8      // independent batch groups (16 rows each)

// Per-producer step flags: one 128-B line per (group, block-role). Layout:
// g_cnt[(g*12 + role)*32]. Value = (steps completed) + 1; 0 until init.
// Zeroed by init_kernel (stream-ordered before the main kernel) every launch.
// Rationale vs r4's two shared counters: a shared counter line serializes
// 8-12 poll-RMWs against the critical arrival-RMW at the L3 bank; per-owner
// lines decouple them (arrivals uncontended, polls spread 12-wide).
__device__ __attribute__((aligned(128))) unsigned int g_cnt[NG * 12 * 32];

typedef __attribute__((ext_vector_type(8))) short short8;
typedef __attribute__((ext_vector_type(4))) float floatx4;

// Split fp32 v into bf16 hi + bf16 lo (residual), packed (hi<<16)|lo.
__device__ __forceinline__ unsigned int split_pack(float v) {
    unsigned int u  = __float_as_uint(v);
    unsigned int hb = u & 0xffff0000u;          // truncated-bf16 hi, exact in fp32
    float r = v - __uint_as_float(hb);          // exact residual
    return hb | (__float_as_uint(r) >> 16);
}

__device__ __forceinline__ float sigmoidf_(float z) {
    return 1.0f / (1.0f + __expf(-z));
}

// ---- r4-proven device-coherent primitives ----
// sc1 stores write through to the coherence point (L2 never dirtied => the
// release arrival's wbl2 is ~free). sc1 u64 loads used ONLY for coalesced
// block-cooperative staging (r3/r9 lesson: per-lane sc1 gathers are L3
// transaction-bound, 2x regression). Relaxed RMW polls execute memory-side
// at L3 (never stale -- r1 lesson, no per-poll cache maintenance -- r0
// lesson). No acquire fence anywhere => weights/x stay L1/L2-warm across all
// 512 steps.
__device__ __forceinline__ void st_coh(unsigned int* p, unsigned int v) {
    __hip_atomic_store(p, v, __ATOMIC_RELAXED, __HIP_MEMORY_SCOPE_AGENT);
}
__device__ __forceinline__ unsigned long long ld_coh64(const unsigned long long* p) {
    return __hip_atomic_load(p, __ATOMIC_RELAXED, __HIP_MEMORY_SCOPE_AGENT);
}
__device__ __forceinline__ unsigned int ld_rmw(unsigned int* p) {
    return __hip_atomic_fetch_add(p, 0u, __ATOMIC_RELAXED, __HIP_MEMORY_SCOPE_AGENT);
}
__device__ __forceinline__ void arrive(unsigned int* flag) {
    __hip_atomic_fetch_add(flag, 1u, __ATOMIC_RELEASE, __HIP_MEMORY_SCOPE_AGENT);
}

// Poll all 12 per-producer flags of the group in one burst (12 independent
// relaxed RMWs issue back-to-back -> ~one L3 round trip per round), until
// min(L1 flags 0..7) >= t1  and  min(L2 flags 8..11) >= t2.
__device__ __forceinline__ void poll12(unsigned int* fb, unsigned int t1, unsigned int t2) {
    for (;;) {
        unsigned int m1 = 0xffffffffu, m2 = 0xffffffffu;
#pragma unroll
        for (int r = 0; r < 8; ++r) {
            unsigned int v = ld_rmw(fb + r * 32);
            if (v < m1) m1 = v;
        }
#pragma unroll
        for (int r = 8; r < 12; ++r) {
            unsigned int v = ld_rmw(fb + r * 32);
            if (v < m2) m2 = v;
        }
        if (m1 >= t1 && m2 >= t2) return;
    }
}

// ---- LDS staging (swizzle: uint col c of row r at c ^ ((r&7)<<2); XOR flips
// bits 2-4 only, so 4-uint-aligned chunks move as units) ----
template<int RS, int NJ>
__device__ __forceinline__ void stage_tile(unsigned int* lds, const unsigned int* gsrc, int tid) {
    const unsigned long long* s64 = (const unsigned long long*)gsrc;
    unsigned long long q[NJ];
#pragma unroll
    for (int j = 0; j < NJ; ++j) q[j] = ld_coh64(s64 + tid + 256 * j);
#pragma unroll
    for (int j = 0; j < NJ; ++j) {
        int f   = tid + 256 * j;
        int row = f / (RS / 2);
        int c   = (f % (RS / 2)) * 2;
        *(unsigned long long*)(lds + row * RS + (c ^ ((row & 7) << 2))) = q[j];
    }
}

// Unpack 8 packed hi/lo uints from swizzled LDS (i0 4-uint aligned; the
// second uint4 of the 8-chunk lives at i0 ^ 4).
__device__ __forceinline__ void unpack_lds(const unsigned int* lp, int i0, short8& ah, short8& al) {
    uint4 pa = *(const uint4*)(lp + i0);
    uint4 pb = *(const uint4*)(lp + (i0 ^ 4));
    unsigned int pv[8] = {pa.x, pa.y, pa.z, pa.w, pb.x, pb.y, pb.z, pb.w};
#pragma unroll
    for (int j = 0; j < 8; ++j) {
        ah[j] = (short)(pv[j] >> 16);
        al[j] = (short)(pv[j] & 0xffffu);
    }
}

__device__ __forceinline__ void cvt_x(const float* xp, short8& ah, short8& al) {
    float4 xa = *(const float4*)(xp);
    float4 xb = *(const float4*)(xp + 4);
    float xv[8] = {xa.x, xa.y, xa.z, xa.w, xb.x, xb.y, xb.z, xb.w};
#pragma unroll
    for (int j = 0; j < 8; ++j) {
        unsigned int u  = __float_as_uint(xv[j]);
        unsigned int hb = u & 0xffff0000u;
        float r = xv[j] - __uint_as_float(hb);
        ah[j] = (short)(u >> 16);
        al[j] = (short)(__float_as_uint(r) >> 16);
    }
}

// One LSTM layer role for one batch group (16 rows). Wave owns the group's
// m-tile x 2 column-tiles (8 units, all 4 gates). Weights pre-split to bf16
// hi/lo MFMA B-fragments in registers.
// MFMA 16x16x32_bf16: A: m=lane&15,k=quad*8+j ; D: col=lane&15, row=quad*4+r
//
// Per-producer-flag dependency schedule (exact translation of r4's counter
// targets; flag = steps completed + 1, init zeros publish = 1):
//   L1@s : wait all L1 flags >= s+1 [peers' h1[s-1]]
//          and  all L2 flags >= s   [h1-slot free: L2 done s-2]
//   L2@s : wait all L1 flags >= s+2 [h1[s] ready]
//          and  all L2 flags >= s+1 [peers' h2[s-1] + h2-slot free]
// Publish after step s: own flag = s+2. DAG identical to r4 => deadlock-free,
// 2-slot ring safety identical.
template<int NKC, int KX, int GW, int UU, bool L1>
__device__ void lstm_role(const float* __restrict__ x,
                          const float* __restrict__ Wm, const float* __restrict__ Um,
                          const float* __restrict__ bias,
                          unsigned int* __restrict__ h1pk, unsigned int* __restrict__ h2pk,
                          float* __restrict__ out,
                          unsigned int* __restrict__ fbase, unsigned int* __restrict__ fown,
                          int m0, int wid, float (*zex)[17],
                          unsigned int* __restrict__ ldsA, unsigned int* __restrict__ ldsB)
{
    const int tid  = threadIdx.x;
    const int lane = tid & 63;
    const int n    = lane & 15;
    const int quad = lane >> 4;
    const int gate = n >> 2;
    const int u0   = wid * 8;             // 8 units per wave (2 coltiles x 4)
    const int arow = m0 + n;              // A-fragment row this lane loads
    const int b_l  = lane >> 2;           // epilogue: batch-local 0..15
    const int ul   = lane & 3;            // epilogue: unit-local 0..3
    const int sw   = (n & 7) << 2;        // LDS read swizzle for this lane's row

    // ---- one-time: weight B-fragments (hi/lo split), bias ----
    short8 bh[2][NKC], bl[2][NKC];
    float bias_v[2];
#pragma unroll
    for (int c = 0; c < 2; ++c) {
        const int col = gate * UU + u0 + c * 4 + (n & 3);
        bias_v[c] = bias[col];
#pragma unroll
        for (int kc = 0; kc < NKC; ++kc) {
#pragma unroll
            for (int j = 0; j < 8; ++j) {
                int k = kc * 32 + quad * 8 + j;
                float w = (k < KX) ? Wm[k * GW + col] : Um[(k - KX) * GW + col];
                unsigned int p = split_pack(w);
                bh[c][kc][j] = (short)(p >> 16);
                bl[c][kc][j] = (short)(p & 0xffffu);
            }
        }
    }

    // ---- zero the "step -1" h slice this wave owns (ws is poisoned) ----
#pragma unroll
    for (int c = 0; c < 2; ++c) {
        if (L1) st_coh(&h1pk[32768 + (m0 + b_l) * 256 + u0 + c * 4 + ul], 0u);
        else    st_coh(&h2pk[16384 + (m0 + b_l) * 128 + u0 + c * 4 + ul], 0u);
    }
    float cst[2] = {0.f, 0.f};

    __syncthreads();                      // drains each wave's zero stores
    if (tid == 0) arrive(fown);           // own flag -> 1 ("step -1 done")

    for (int s = 0; s < 512; ++s) {
        // ---- pre-poll: acc init + L1 x-part (cache-resident, no recurrent
        // dependency) stays off the post-observe critical path ----
        floatx4 acc[2];
#pragma unroll
        for (int c = 0; c < 2; ++c)
            acc[c] = {bias_v[c], bias_v[c], bias_v[c], bias_v[c]};
        if (L1) {
            const float* xsrc = x + (size_t)arow * (512 * 64) + s * 64;
#pragma unroll
            for (int kc = 0; kc < 2; ++kc) {
                short8 ah, al;
                cvt_x(xsrc + kc * 32 + quad * 8, ah, al);
#pragma unroll
                for (int c = 0; c < 2; ++c) {
                    acc[c] = __builtin_amdgcn_mfma_f32_16x16x32_bf16(ah, bh[c][kc], acc[c], 0, 0, 0);
                    acc[c] = __builtin_amdgcn_mfma_f32_16x16x32_bf16(ah, bl[c][kc], acc[c], 0, 0, 0);
                    acc[c] = __builtin_amdgcn_mfma_f32_16x16x32_bf16(al, bh[c][kc], acc[c], 0, 0, 0);
                }
            }
        }

        // ---- wait for inputs (thread 0 polls flag burst; barrier
        // publishes the observation to the block) ----
        if (tid == 0) {
            if (L1) poll12(fbase, (unsigned)(s + 1), (unsigned)s);
            else    poll12(fbase, (unsigned)(s + 2), (unsigned)(s + 1));
        }
        __syncthreads();

        // ---- block-cooperative staging of h tiles into swizzled LDS ----
        if (L1) {
            stage_tile<256, 8>(ldsA, h1pk + ((s + 1) & 1) * 32768 + m0 * 256, tid);  // h1[s-1]
        } else {
            stage_tile<256, 8>(ldsA, h1pk + (s & 1) * 32768 + m0 * 256, tid);        // h1[s]
            stage_tile<128, 4>(ldsB, h2pk + ((s + 1) & 1) * 16384 + m0 * 128, tid);  // h2[s-1]
        }
        __syncthreads();

        // ---- recurrent MFMAs ----
#pragma unroll
        for (int kc = (L1 ? 2 : 0); kc < NKC; ++kc) {
            short8 ah, al;
            if (L1)          unpack_lds(ldsA, n * 256 + (((kc - 2) * 32 + quad * 8) ^ sw), ah, al);
            else if (kc < 8) unpack_lds(ldsA, n * 256 + ((kc * 32 + quad * 8) ^ sw), ah, al);
            else             unpack_lds(ldsB, n * 128 + (((kc - 8) * 32 + quad * 8) ^ sw), ah, al);
#pragma unroll
            for (int c = 0; c < 2; ++c) {
                acc[c] = __builtin_amdgcn_mfma_f32_16x16x32_bf16(ah, bh[c][kc], acc[c], 0, 0, 0);
                acc[c] = __builtin_amdgcn_mfma_f32_16x16x32_bf16(ah, bl[c][kc], acc[c], 0, 0, 0);
                acc[c] = __builtin_amdgcn_mfma_f32_16x16x32_bf16(al, bh[c][kc], acc[c], 0, 0, 0);
            }
        }

        // ---- epilogue: per coltile, gate-gather via per-wave LDS tile.
        // Wave-level lgkmcnt(0) drains the ds_writes of ALL lanes of this
        // wave before any lane's read; memory clobber stops reordering. ----
#pragma unroll
        for (int c = 0; c < 2; ++c) {
#pragma unroll
            for (int r = 0; r < 4; ++r) zex[quad * 4 + r][n] = acc[c][r];
            asm volatile("s_waitcnt lgkmcnt(0)" ::: "memory");
            float zi = zex[b_l][ 0 + ul];
            float zf = zex[b_l][ 4 + ul];
            float zg = zex[b_l][ 8 + ul];
            float zo = zex[b_l][12 + ul];
            asm volatile("s_waitcnt lgkmcnt(0)" ::: "memory");
            float ig = sigmoidf_(zi);
            float fg = sigmoidf_(zf);
            float gg = fmaxf(zg, 0.f);
            float og = sigmoidf_(zo);
            cst[c] = fg * cst[c] + ig * gg;
            float h = og * fmaxf(cst[c], 0.f);
            unsigned int p = split_pack(h);
            int b = m0 + b_l;
            if (L1) {
                st_coh(&h1pk[(s & 1) * 32768 + b * 256 + u0 + c * 4 + ul], p);
            } else {
                st_coh(&h2pk[(s & 1) * 16384 + b * 128 + u0 + c * 4 + ul], p);
                if (s == 511) out[b * 128 + u0 + c * 4 + ul] = h;
            }
        }

        // ---- publish: barrier drains all waves' sc1 stores (per-wave
        // vmcnt(0) before s_barrier), then one release arrival on the
        // block's OWN flag line (uncontended) ----
        __syncthreads();
        if (tid == 0) arrive(fown);
    }
}

__global__ void __launch_bounds__(256, 1)
lstm_fused_kernel(const float* __restrict__ x,
                  const float* __restrict__ W1, const float* __restrict__ U1,
                  const float* __restrict__ b1,
                  const float* __restrict__ W2, const float* __restrict__ U2,
                  const float* __restrict__ b2,
                  float* __restrict__ out, unsigned int* __restrict__ ws)
{
    __shared__ float zex[4][16][17];         // per-wave gate-gather tiles
    __shared__ unsigned int ldsA[16 * 256];  // staged h1 tile (swizzled)
    __shared__ unsigned int ldsB[16 * 128];  // staged h2 tile (swizzled, L2-role)
    unsigned int* h1pk = ws;                 // [2][128][256] packed hi/lo bf16
    unsigned int* h2pk = ws + 65536;         // [2][128][128]
    const int g    = blockIdx.x & 7;         // batch group
    const int role = blockIdx.x >> 3;        // 0..7 layer1, 8..11 layer2
    const int wv   = threadIdx.x >> 6;
    const int m0   = g * 16;
    unsigned int* fbase = &g_cnt[g * 12 * 32];
    unsigned int* fown  = fbase + role * 32;
    if (role < 8) {
        // layer1: 8 blocks x 4 waves = 32 unit-waves x 8 units = 256 units
        lstm_role<10, 64, 1024, 256, true >(x, W1, U1, b1, h1pk, h2pk, out,
                                            fbase, fown, m0, role * 4 + wv, zex[wv], ldsA, ldsB);
    } else {
        // layer2: 4 blocks x 4 waves = 16 unit-waves x 8 units = 128 units
        lstm_role<12, 256, 512, 128, false>(x, W2, U2, b2, h1pk, h2pk, out,
                                            fbase, fown, m0, (role - 8) * 4 + wv, zex[wv], ldsA, ldsB);
    }
}

// Pre-kernel (plain launch, cannot fail): zero flags, write the diagnostic
// sentinel. Stream order publishes both to the main kernel.
// Failure signatures: absmax~7 => main never ran (launch issue);
// absmax~0.162 => main ran but produced zeros (coherence issue).
__global__ void init_kernel(float* __restrict__ out) {
    int t = blockIdx.x * 256 + threadIdx.x;
    if (t < NG * 12 * 32) g_cnt[t] = 0u;
    if (t < 16384) out[t] = 7.0f;
}

extern "C" void kernel_launch(void* const* d_in, const int* in_sizes, int n_in,
                              void* d_out, int out_size, void* d_ws, size_t ws_size,
                              hipStream_t stream) {
    const float* x  = (const float*)d_in[0];
    const float* W1 = (const float*)d_in[1];
    const float* U1 = (const float*)d_in[2];
    const float* b1 = (const float*)d_in[3];
    const float* W2 = (const float*)d_in[4];
    const float* U2 = (const float*)d_in[5];
    const float* b2 = (const float*)d_in[6];
    float* out = (float*)d_out;
    unsigned int* ws = (unsigned int*)d_ws;
    init_kernel<<<64, 256, 0, stream>>>(out);
    lstm_fused_kernel<<<96, 256, 0, stream>>>(x, W1, U1, b1, W2, U2, b2, out, ws);
}